// Round 1
// baseline (6147.075 us; speedup 1.0000x reference)
//
#include <hip/hip_runtime.h>
#include <hip/hip_bf16.h>

#define USER_NUM 100000
#define ITEM_NUM 50000
#define NNODES   150000
#define DIM      64
#define NEDGES   2400000
#define NLAYERS  3
#define BATCH    4096

// ---------------------------------------------------------------------------
// init: cur = acc = concat(user_emb, item_emb), float4-vectorized
// ---------------------------------------------------------------------------
__global__ void init_kernel(const float* __restrict__ user_emb,
                            const float* __restrict__ item_emb,
                            float* __restrict__ cur,
                            float* __restrict__ acc) {
    const long total4 = (long)NNODES * DIM / 4;           // 2.4M float4
    long i = (long)blockIdx.x * blockDim.x + threadIdx.x;
    if (i >= total4) return;
    const long user4 = (long)USER_NUM * DIM / 4;          // 1.6M float4
    float4 v;
    if (i < user4) v = ((const float4*)user_emb)[i];
    else           v = ((const float4*)item_emb)[i - user4];
    ((float4*)cur)[i] = v;
    ((float4*)acc)[i] = v;
}

// ---------------------------------------------------------------------------
// scatter: next[dst] += val * cur[src]; 16 threads per edge, 4 dims each
// ---------------------------------------------------------------------------
__global__ void scatter_kernel(const int* __restrict__ edge_src,
                               const int* __restrict__ edge_dst,
                               const float* __restrict__ edge_val,
                               const float* __restrict__ cur,
                               float* __restrict__ next) {
    long t = (long)blockIdx.x * blockDim.x + threadIdx.x;
    int e = (int)(t >> 4);
    if (e >= NEDGES) return;
    int k = ((int)t & 15) * 4;
    int src = edge_src[e];
    int dst = edge_dst[e];
    float val = edge_val[e];
    float4 v = *(const float4*)&cur[(long)src * DIM + k];
    float* o = &next[(long)dst * DIM + k];
    atomicAdd(o + 0, val * v.x);
    atomicAdd(o + 1, val * v.y);
    atomicAdd(o + 2, val * v.z);
    atomicAdd(o + 3, val * v.w);
}

// ---------------------------------------------------------------------------
// acc += next (float4)
// ---------------------------------------------------------------------------
__global__ void add_kernel(float* __restrict__ acc,
                           const float* __restrict__ next) {
    const long total4 = (long)NNODES * DIM / 4;
    long i = (long)blockIdx.x * blockDim.x + threadIdx.x;
    if (i >= total4) return;
    float4 a = ((float4*)acc)[i];
    float4 b = ((const float4*)next)[i];
    a.x += b.x; a.y += b.y; a.z += b.z; a.w += b.w;
    ((float4*)acc)[i] = a;
}

// ---------------------------------------------------------------------------
// epilogue: one wave per batch elem; gamma = dot(acc_u, acc_i)/16; sigmoid
// ---------------------------------------------------------------------------
__global__ void dot_kernel(const float* __restrict__ acc,
                           const int* __restrict__ users,
                           const int* __restrict__ items,
                           float* __restrict__ out) {
    int w = (int)(((long)blockIdx.x * blockDim.x + threadIdx.x) >> 6);
    int lane = threadIdx.x & 63;
    if (w >= BATCH) return;
    int u = users[w];
    int it = items[w];
    float a = acc[(long)u * DIM + lane];
    float b = acc[((long)USER_NUM + it) * DIM + lane];
    float p = a * b;
    #pragma unroll
    for (int off = 32; off; off >>= 1) p += __shfl_down(p, off);
    if (lane == 0) {
        float gamma = p * (1.0f / 16.0f);   // mean = acc/4 on both sides
        out[w] = 1.0f / (1.0f + __expf(-gamma));
    }
}

extern "C" void kernel_launch(void* const* d_in, const int* in_sizes, int n_in,
                              void* d_out, int out_size, void* d_ws, size_t ws_size,
                              hipStream_t stream) {
    const float* user_emb = (const float*)d_in[0];
    const float* item_emb = (const float*)d_in[1];
    const int*   edge_src = (const int*)d_in[2];
    const int*   edge_dst = (const int*)d_in[3];
    const float* edge_val = (const float*)d_in[4];
    const int*   users    = (const int*)d_in[5];
    const int*   items    = (const int*)d_in[6];
    float* out = (float*)d_out;

    const size_t tbl_bytes = (size_t)NNODES * DIM * sizeof(float); // 38.4 MB
    float* acc  = (float*)d_ws;
    float* bufA = (float*)((char*)d_ws + tbl_bytes);
    float* bufB = (float*)((char*)d_ws + 2 * tbl_bytes);

    // init: cur=bufA, acc
    {
        long total4 = (long)NNODES * DIM / 4;
        int block = 256;
        long grid = (total4 + block - 1) / block;
        init_kernel<<<(dim3)(unsigned)grid, block, 0, stream>>>(user_emb, item_emb, bufA, acc);
    }

    float* cur = bufA;
    float* next = bufB;
    for (int l = 0; l < NLAYERS; ++l) {
        hipMemsetAsync(next, 0, tbl_bytes, stream);
        {
            long total = (long)NEDGES * 16;
            int block = 256;
            long grid = (total + block - 1) / block;
            scatter_kernel<<<(dim3)(unsigned)grid, block, 0, stream>>>(
                edge_src, edge_dst, edge_val, cur, next);
        }
        {
            long total4 = (long)NNODES * DIM / 4;
            int block = 256;
            long grid = (total4 + block - 1) / block;
            add_kernel<<<(dim3)(unsigned)grid, block, 0, stream>>>(acc, next);
        }
        float* tmp = cur; cur = next; next = tmp;
    }

    {
        long total = (long)BATCH * 64;
        int block = 256;
        long grid = (total + block - 1) / block;
        dot_kernel<<<(dim3)(unsigned)grid, block, 0, stream>>>(acc, users, items, out);
    }
}

// Round 2
// 577.763 us; speedup vs baseline: 10.6394x; 10.6394x over previous
//
#include <hip/hip_runtime.h>
#include <hip/hip_bf16.h>

#define USER_NUM 100000
#define ITEM_NUM 50000
#define NNODES   150000
#define DIM      64
#define NEDGES   2400000
#define NLAYERS  3
#define BATCH    4096

#define SCAN_B   1024
#define SCAN_G   ((NNODES + SCAN_B - 1) / SCAN_B)   // 147

// ---------------------------------------------------------------------------
// init: cur = acc = concat(user_emb, item_emb), float4-vectorized
// ---------------------------------------------------------------------------
__global__ void init_kernel(const float* __restrict__ user_emb,
                            const float* __restrict__ item_emb,
                            float* __restrict__ cur,
                            float* __restrict__ acc) {
    const long total4 = (long)NNODES * DIM / 4;
    long i = (long)blockIdx.x * blockDim.x + threadIdx.x;
    if (i >= total4) return;
    const long user4 = (long)USER_NUM * DIM / 4;
    float4 v;
    if (i < user4) v = ((const float4*)user_emb)[i];
    else           v = ((const float4*)item_emb)[i - user4];
    ((float4*)cur)[i] = v;
    ((float4*)acc)[i] = v;
}

// ---------------------------------------------------------------------------
// CSR build: histogram -> 2-level exclusive scan -> counting-sort scatter
// ---------------------------------------------------------------------------
__global__ void hist_kernel(const int* __restrict__ edge_dst, int* __restrict__ cnt) {
    int e = blockIdx.x * blockDim.x + threadIdx.x;
    if (e < NEDGES) atomicAdd(&cnt[edge_dst[e]], 1);
}

__global__ void scan1_kernel(const int* __restrict__ cnt,
                             int* __restrict__ incl, int* __restrict__ bsums) {
    __shared__ int s[SCAN_B];
    int i = blockIdx.x * SCAN_B + threadIdx.x;
    int v = (i < NNODES) ? cnt[i] : 0;
    s[threadIdx.x] = v;
    __syncthreads();
    for (int off = 1; off < SCAN_B; off <<= 1) {
        int t = (threadIdx.x >= off) ? s[threadIdx.x - off] : 0;
        __syncthreads();
        s[threadIdx.x] += t;
        __syncthreads();
    }
    if (i < NNODES) incl[i] = s[threadIdx.x];
    if (threadIdx.x == SCAN_B - 1) bsums[blockIdx.x] = s[SCAN_B - 1];
}

__global__ void scan2_kernel(int* __restrict__ bsums) {  // one block of 256, n=SCAN_G<=256
    __shared__ int s[256];
    int v = (threadIdx.x < SCAN_G) ? bsums[threadIdx.x] : 0;
    s[threadIdx.x] = v;
    __syncthreads();
    for (int off = 1; off < 256; off <<= 1) {
        int t = (threadIdx.x >= off) ? s[threadIdx.x - off] : 0;
        __syncthreads();
        s[threadIdx.x] += t;
        __syncthreads();
    }
    if (threadIdx.x < SCAN_G) bsums[threadIdx.x] = s[threadIdx.x];
}

__global__ void scan3_kernel(const int* __restrict__ incl, const int* __restrict__ bsums,
                             const int* __restrict__ cnt, int* __restrict__ row_ptr) {
    int i = blockIdx.x * blockDim.x + threadIdx.x;
    if (i >= NNODES) return;
    int b = i / SCAN_B;
    int off = (b > 0) ? bsums[b - 1] : 0;
    row_ptr[i] = off + incl[i] - cnt[i];           // exclusive
    if (i == 0) row_ptr[NNODES] = NEDGES;
}

__global__ void sort_kernel(const int* __restrict__ edge_src,
                            const int* __restrict__ edge_dst,
                            const float* __restrict__ edge_val,
                            const int* __restrict__ row_ptr,
                            int* __restrict__ fill,
                            int2* __restrict__ sedge) {
    int e = blockIdx.x * blockDim.x + threadIdx.x;
    if (e >= NEDGES) return;
    int d = edge_dst[e];
    int pos = row_ptr[d] + atomicAdd(&fill[d], 1);
    sedge[pos] = make_int2(edge_src[e], __float_as_int(edge_val[e]));
}

// ---------------------------------------------------------------------------
// gather SpMM: 16 lanes per dst row, each owns a float4 of the 64-dim row.
// next[d] = sum val*cur[src];  acc[d] += next[d].  No atomics, no memset.
// ---------------------------------------------------------------------------
template<bool WRITE_NEXT>
__global__ void spmm_kernel(const int* __restrict__ row_ptr,
                            const int2* __restrict__ sedge,
                            const float* __restrict__ cur,
                            float* __restrict__ next,
                            float* __restrict__ acc) {
    long t = (long)blockIdx.x * blockDim.x + threadIdx.x;
    int row = (int)(t >> 4);
    if (row >= NNODES) return;
    int k = ((int)t & 15) * 4;
    int start = row_ptr[row];
    int end   = row_ptr[row + 1];
    float4 s = make_float4(0.f, 0.f, 0.f, 0.f);
    for (int j = start; j < end; ++j) {
        int2 e = sedge[j];
        float v = __int_as_float(e.y);
        float4 x = *(const float4*)&cur[(long)e.x * DIM + k];
        s.x += v * x.x; s.y += v * x.y; s.z += v * x.z; s.w += v * x.w;
    }
    long o = (long)row * DIM + k;
    if (WRITE_NEXT) *(float4*)&next[o] = s;
    float4 a = *(float4*)&acc[o];
    a.x += s.x; a.y += s.y; a.z += s.z; a.w += s.w;
    *(float4*)&acc[o] = a;
}

// ---------------------------------------------------------------------------
// epilogue: one wave per batch elem; gamma = dot(acc_u, acc_i)/16; sigmoid
// ---------------------------------------------------------------------------
__global__ void dot_kernel(const float* __restrict__ acc,
                           const int* __restrict__ users,
                           const int* __restrict__ items,
                           float* __restrict__ out) {
    int w = (int)(((long)blockIdx.x * blockDim.x + threadIdx.x) >> 6);
    int lane = threadIdx.x & 63;
    if (w >= BATCH) return;
    int u = users[w];
    int it = items[w];
    float a = acc[(long)u * DIM + lane];
    float b = acc[((long)USER_NUM + it) * DIM + lane];
    float p = a * b;
    #pragma unroll
    for (int off = 32; off; off >>= 1) p += __shfl_down(p, off);
    if (lane == 0) {
        float gamma = p * (1.0f / 16.0f);
        out[w] = 1.0f / (1.0f + __expf(-gamma));
    }
}

extern "C" void kernel_launch(void* const* d_in, const int* in_sizes, int n_in,
                              void* d_out, int out_size, void* d_ws, size_t ws_size,
                              hipStream_t stream) {
    const float* user_emb = (const float*)d_in[0];
    const float* item_emb = (const float*)d_in[1];
    const int*   edge_src = (const int*)d_in[2];
    const int*   edge_dst = (const int*)d_in[3];
    const float* edge_val = (const float*)d_in[4];
    const int*   users    = (const int*)d_in[5];
    const int*   items    = (const int*)d_in[6];
    float* out = (float*)d_out;

    const size_t tbl = (size_t)NNODES * DIM * sizeof(float);  // 38.4 MB
    char* w = (char*)d_ws;
    float* acc     = (float*)w;                 w += tbl;
    float* bufA    = (float*)w;                 w += tbl;
    float* bufB    = (float*)w;                 w += tbl;
    int*   cnt     = (int*)w;                   w += ((size_t)NNODES + 64) * 4;
    int*   incl    = (int*)w;                   w += ((size_t)NNODES + 64) * 4;
    int*   row_ptr = (int*)w;                   w += ((size_t)NNODES + 64) * 4;
    int*   bsums   = (int*)w;                   w += 4096;
    int2*  sedge   = (int2*)w;                  w += (size_t)NEDGES * 8;

    // ---- CSR build (by dst) ----
    hipMemsetAsync(cnt, 0, (size_t)NNODES * 4, stream);
    hist_kernel<<<(NEDGES + 255) / 256, 256, 0, stream>>>(edge_dst, cnt);
    scan1_kernel<<<SCAN_G, SCAN_B, 0, stream>>>(cnt, incl, bsums);
    scan2_kernel<<<1, 256, 0, stream>>>(bsums);
    scan3_kernel<<<(NNODES + 255) / 256, 256, 0, stream>>>(incl, bsums, cnt, row_ptr);
    hipMemsetAsync(cnt, 0, (size_t)NNODES * 4, stream);   // reuse as fill
    sort_kernel<<<(NEDGES + 255) / 256, 256, 0, stream>>>(
        edge_src, edge_dst, edge_val, row_ptr, cnt, sedge);

    // ---- init ----
    {
        long total4 = (long)NNODES * DIM / 4;
        init_kernel<<<(unsigned)((total4 + 255) / 256), 256, 0, stream>>>(
            user_emb, item_emb, bufA, acc);
    }

    // ---- 3 SpMM layers (gather, fused acc) ----
    const unsigned spmm_grid = (unsigned)(((long)NNODES * 16 + 255) / 256);
    spmm_kernel<true ><<<spmm_grid, 256, 0, stream>>>(row_ptr, sedge, bufA, bufB, acc);
    spmm_kernel<true ><<<spmm_grid, 256, 0, stream>>>(row_ptr, sedge, bufB, bufA, acc);
    spmm_kernel<false><<<spmm_grid, 256, 0, stream>>>(row_ptr, sedge, bufA, bufB, acc);

    // ---- epilogue ----
    dot_kernel<<<(BATCH * 64 + 255) / 256, 256, 0, stream>>>(acc, users, items, out);
}

// Round 3
// 452.216 us; speedup vs baseline: 13.5932x; 1.2776x over previous
//
#include <hip/hip_runtime.h>
#include <hip/hip_bf16.h>

#define USER_NUM 100000
#define ITEM_NUM 50000
#define NNODES   150000
#define DIM      64
#define NEDGES   2400000
#define BATCH    4096

#define NPB      128                          // nodes per bucket (dst>>7)
#define NB       ((NNODES + NPB - 1) / NPB)   // 1172 buckets
#define CHUNK    8192
#define NBLK     ((NEDGES + CHUNK - 1) / CHUNK)  // 293 blocks
#define SEG      5                            // 256*5 = 1280 >= NB

// ---------------------------------------------------------------------------
// init: cur = acc = concat(user_emb, item_emb), float4-vectorized
// ---------------------------------------------------------------------------
__global__ void init_kernel(const float* __restrict__ user_emb,
                            const float* __restrict__ item_emb,
                            float* __restrict__ cur,
                            float* __restrict__ acc) {
    const long total4 = (long)NNODES * DIM / 4;
    long i = (long)blockIdx.x * blockDim.x + threadIdx.x;
    if (i >= total4) return;
    const long user4 = (long)USER_NUM * DIM / 4;
    float4 v;
    if (i < user4) v = ((const float4*)user_emb)[i];
    else           v = ((const float4*)item_emb)[i - user4];
    ((float4*)cur)[i] = v;
    ((float4*)acc)[i] = v;
}

// ---------------------------------------------------------------------------
// CSR build, two-level bucketed counting sort.
// K2: per-block LDS hist of dst-buckets -> global bucket_cnt
// ---------------------------------------------------------------------------
__global__ void bucket_hist_kernel(const int* __restrict__ edge_dst,
                                   int* __restrict__ bucket_cnt) {
    __shared__ int h[NB];
    for (int t = threadIdx.x; t < NB; t += blockDim.x) h[t] = 0;
    __syncthreads();
    int lo = blockIdx.x * CHUNK;
    int hi = min(lo + CHUNK, NEDGES);
    for (int j = lo + (int)threadIdx.x; j < hi; j += blockDim.x)
        atomicAdd(&h[edge_dst[j] >> 7], 1);
    __syncthreads();
    for (int t = threadIdx.x; t < NB; t += blockDim.x)
        if (h[t]) atomicAdd(&bucket_cnt[t], h[t]);
}

// K3: exclusive scan of bucket_cnt (NB=1172) in one block -> bucket_base, fill
__global__ void bucket_scan_kernel(const int* __restrict__ bucket_cnt,
                                   int* __restrict__ bucket_base,
                                   int* __restrict__ fill,
                                   int* __restrict__ row_ptr) {
    __shared__ int s[256 * SEG];
    __shared__ int ss[256];
    int tid = threadIdx.x;
    for (int t = tid; t < 256 * SEG; t += 256) s[t] = (t < NB) ? bucket_cnt[t] : 0;
    __syncthreads();
    int sum = 0;
    #pragma unroll
    for (int k = 0; k < SEG; ++k) {       // exclusive scan within segment
        int v = s[tid * SEG + k];
        s[tid * SEG + k] = sum;
        sum += v;
    }
    ss[tid] = sum;
    __syncthreads();
    for (int off = 1; off < 256; off <<= 1) {   // inclusive scan of seg sums
        int t = (tid >= off) ? ss[tid - off] : 0;
        __syncthreads();
        ss[tid] += t;
        __syncthreads();
    }
    int segoff = (tid > 0) ? ss[tid - 1] : 0;
    #pragma unroll
    for (int k = 0; k < SEG; ++k) s[tid * SEG + k] += segoff;
    __syncthreads();
    for (int t = tid; t < NB; t += 256) {
        bucket_base[t] = s[t];
        fill[t] = s[t];
    }
    if (tid == 0) {
        bucket_base[NB] = NEDGES;
        row_ptr[NNODES] = NEDGES;
    }
}

// K4: partition edges into bucket-contiguous tmp arrays
__global__ void partition_kernel(const int* __restrict__ edge_src,
                                 const int* __restrict__ edge_dst,
                                 const float* __restrict__ edge_val,
                                 int* __restrict__ fill,
                                 int* __restrict__ tmp_dst,
                                 int2* __restrict__ tmp_sv) {
    __shared__ int h[NB];
    for (int t = threadIdx.x; t < NB; t += blockDim.x) h[t] = 0;
    __syncthreads();
    int lo = blockIdx.x * CHUNK;
    int hi = min(lo + CHUNK, NEDGES);
    for (int j = lo + (int)threadIdx.x; j < hi; j += blockDim.x)
        atomicAdd(&h[edge_dst[j] >> 7], 1);
    __syncthreads();
    for (int t = threadIdx.x; t < NB; t += blockDim.x) {
        int c = h[t];
        h[t] = c ? atomicAdd(&fill[t], c) : 0;   // LDS cursor = my base
    }
    __syncthreads();
    for (int j = lo + (int)threadIdx.x; j < hi; j += blockDim.x) {
        int d = edge_dst[j];
        int pos = atomicAdd(&h[d >> 7], 1);
        tmp_dst[pos] = d;
        tmp_sv[pos]  = make_int2(edge_src[j], __float_as_int(edge_val[j]));
    }
}

// K5: per-bucket local counting sort (128 nodes) -> row_ptr + sorted sedge
__global__ void local_sort_kernel(const int* __restrict__ bucket_base,
                                  const int* __restrict__ tmp_dst,
                                  const int2* __restrict__ tmp_sv,
                                  int* __restrict__ row_ptr,
                                  int2* __restrict__ sedge) {
    __shared__ int h[NPB];
    __shared__ int sc[NPB];
    __shared__ int cur[NPB];
    int b = blockIdx.x;
    int base = bucket_base[b];
    int end  = bucket_base[b + 1];
    int i = threadIdx.x;
    if (i < NPB) h[i] = 0;
    __syncthreads();
    for (int j = base + i; j < end; j += blockDim.x)
        atomicAdd(&h[tmp_dst[j] & (NPB - 1)], 1);
    __syncthreads();
    if (i < NPB) sc[i] = h[i];
    __syncthreads();
    for (int off = 1; off < NPB; off <<= 1) {
        int t = (i < NPB && i >= off) ? sc[i - off] : 0;
        __syncthreads();
        if (i < NPB) sc[i] += t;
        __syncthreads();
    }
    if (i < NPB) {
        int excl = sc[i] - h[i];
        cur[i] = base + excl;
        int node = b * NPB + i;
        if (node < NNODES) row_ptr[node] = base + excl;
    }
    __syncthreads();
    for (int j = base + i; j < end; j += blockDim.x) {
        int d = tmp_dst[j];
        int2 sv = tmp_sv[j];
        int pos = atomicAdd(&cur[d & (NPB - 1)], 1);
        sedge[pos] = sv;
    }
}

// ---------------------------------------------------------------------------
// gather SpMM: 16 lanes per dst row, each owns a float4 of the 64-dim row.
// ---------------------------------------------------------------------------
template<bool WRITE_NEXT>
__global__ void spmm_kernel(const int* __restrict__ row_ptr,
                            const int2* __restrict__ sedge,
                            const float* __restrict__ cur,
                            float* __restrict__ next,
                            float* __restrict__ acc) {
    long t = (long)blockIdx.x * blockDim.x + threadIdx.x;
    int row = (int)(t >> 4);
    if (row >= NNODES) return;
    int k = ((int)t & 15) * 4;
    int start = row_ptr[row];
    int end   = row_ptr[row + 1];
    float4 s = make_float4(0.f, 0.f, 0.f, 0.f);
    for (int j = start; j < end; ++j) {
        int2 e = sedge[j];
        float v = __int_as_float(e.y);
        float4 x = *(const float4*)&cur[(long)e.x * DIM + k];
        s.x += v * x.x; s.y += v * x.y; s.z += v * x.z; s.w += v * x.w;
    }
    long o = (long)row * DIM + k;
    if (WRITE_NEXT) *(float4*)&next[o] = s;
    float4 a = *(float4*)&acc[o];
    a.x += s.x; a.y += s.y; a.z += s.z; a.w += s.w;
    *(float4*)&acc[o] = a;
}

// ---------------------------------------------------------------------------
// epilogue: one wave per batch elem; gamma = dot(acc_u, acc_i)/16; sigmoid
// ---------------------------------------------------------------------------
__global__ void dot_kernel(const float* __restrict__ acc,
                           const int* __restrict__ users,
                           const int* __restrict__ items,
                           float* __restrict__ out) {
    int w = (int)(((long)blockIdx.x * blockDim.x + threadIdx.x) >> 6);
    int lane = threadIdx.x & 63;
    if (w >= BATCH) return;
    int u = users[w];
    int it = items[w];
    float a = acc[(long)u * DIM + lane];
    float b = acc[((long)USER_NUM + it) * DIM + lane];
    float p = a * b;
    #pragma unroll
    for (int off = 32; off; off >>= 1) p += __shfl_down(p, off);
    if (lane == 0) {
        float gamma = p * (1.0f / 16.0f);
        out[w] = 1.0f / (1.0f + __expf(-gamma));
    }
}

extern "C" void kernel_launch(void* const* d_in, const int* in_sizes, int n_in,
                              void* d_out, int out_size, void* d_ws, size_t ws_size,
                              hipStream_t stream) {
    const float* user_emb = (const float*)d_in[0];
    const float* item_emb = (const float*)d_in[1];
    const int*   edge_src = (const int*)d_in[2];
    const int*   edge_dst = (const int*)d_in[3];
    const float* edge_val = (const float*)d_in[4];
    const int*   users    = (const int*)d_in[5];
    const int*   items    = (const int*)d_in[6];
    float* out = (float*)d_out;

    const size_t tbl = (size_t)NNODES * DIM * sizeof(float);  // 38.4 MB
    char* w = (char*)d_ws;
    float* acc         = (float*)w;  w += tbl;
    float* bufA        = (float*)w;  w += tbl;
    float* bufB        = (float*)w;  w += tbl;
    int2*  sedge       = (int2*)w;   w += (size_t)NEDGES * 8;
    int*   row_ptr     = (int*)w;    w += ((size_t)NNODES + 16) * 4;
    int*   bucket_cnt  = (int*)w;    w += ((size_t)NB + 8) * 4;
    int*   bucket_base = (int*)w;    w += ((size_t)NB + 8) * 4;
    int*   fill        = (int*)w;    w += ((size_t)NB + 8) * 4;
    // tmp arrays alias bufA/bufB: dead once local_sort completes, before init
    int*   tmp_dst = (int*)bufA;     // 9.6 MB
    int2*  tmp_sv  = (int2*)bufB;    // 19.2 MB

    // ---- CSR build ----
    hipMemsetAsync(bucket_cnt, 0, (size_t)NB * 4, stream);
    bucket_hist_kernel<<<NBLK, 256, 0, stream>>>(edge_dst, bucket_cnt);
    bucket_scan_kernel<<<1, 256, 0, stream>>>(bucket_cnt, bucket_base, fill, row_ptr);
    partition_kernel<<<NBLK, 256, 0, stream>>>(edge_src, edge_dst, edge_val,
                                               fill, tmp_dst, tmp_sv);
    local_sort_kernel<<<NB, 256, 0, stream>>>(bucket_base, tmp_dst, tmp_sv,
                                              row_ptr, sedge);

    // ---- init (after tmp aliases are dead) ----
    {
        long total4 = (long)NNODES * DIM / 4;
        init_kernel<<<(unsigned)((total4 + 255) / 256), 256, 0, stream>>>(
            user_emb, item_emb, bufA, acc);
    }

    // ---- 3 SpMM layers (gather, fused acc) ----
    const unsigned spmm_grid = (unsigned)(((long)NNODES * 16 + 255) / 256);
    spmm_kernel<true ><<<spmm_grid, 256, 0, stream>>>(row_ptr, sedge, bufA, bufB, acc);
    spmm_kernel<true ><<<spmm_grid, 256, 0, stream>>>(row_ptr, sedge, bufB, bufA, acc);
    spmm_kernel<false><<<spmm_grid, 256, 0, stream>>>(row_ptr, sedge, bufA, bufB, acc);

    // ---- epilogue ----
    dot_kernel<<<(BATCH * 64 + 255) / 256, 256, 0, stream>>>(acc, users, items, out);
}

// Round 4
// 447.662 us; speedup vs baseline: 13.7315x; 1.0102x over previous
//
#include <hip/hip_runtime.h>
#include <hip/hip_bf16.h>

#define USER_NUM 100000
#define ITEM_NUM 50000
#define NNODES   150000
#define DIM      64
#define NEDGES   2400000
#define BATCH    4096

#define SPN      512                            // nodes per super-bucket (dst>>9)
#define NSUP     ((NNODES + SPN - 1) / SPN)     // 293 super-buckets
#define CHUNK    8192
#define NBLK     ((NEDGES + CHUNK - 1) / CHUNK) // 293 blocks

// ---------------------------------------------------------------------------
// init: cur = acc = concat(user_emb, item_emb), float4-vectorized
// ---------------------------------------------------------------------------
__global__ void init_kernel(const float* __restrict__ user_emb,
                            const float* __restrict__ item_emb,
                            float* __restrict__ cur,
                            float* __restrict__ acc) {
    const long total4 = (long)NNODES * DIM / 4;
    long i = (long)blockIdx.x * blockDim.x + threadIdx.x;
    if (i >= total4) return;
    const long user4 = (long)USER_NUM * DIM / 4;
    float4 v;
    if (i < user4) v = ((const float4*)user_emb)[i];
    else           v = ((const float4*)item_emb)[i - user4];
    ((float4*)cur)[i] = v;
    ((float4*)acc)[i] = v;
}

// ---------------------------------------------------------------------------
// K2: per-block LDS hist of dst super-buckets -> global bucket_cnt
// ---------------------------------------------------------------------------
__global__ void bucket_hist_kernel(const int* __restrict__ edge_dst,
                                   int* __restrict__ bucket_cnt) {
    __shared__ int h[NSUP];
    for (int t = threadIdx.x; t < NSUP; t += blockDim.x) h[t] = 0;
    __syncthreads();
    int lo = blockIdx.x * CHUNK;
    int hi = min(lo + CHUNK, NEDGES);
    for (int j = lo + (int)threadIdx.x; j < hi; j += blockDim.x)
        atomicAdd(&h[edge_dst[j] >> 9], 1);
    __syncthreads();
    for (int t = threadIdx.x; t < NSUP; t += blockDim.x)
        if (h[t]) atomicAdd(&bucket_cnt[t], h[t]);
}

// ---------------------------------------------------------------------------
// K3: exclusive scan of bucket_cnt (NSUP=293) in one block, 2 elems/thread
// ---------------------------------------------------------------------------
__global__ void bucket_scan_kernel(const int* __restrict__ bucket_cnt,
                                   int* __restrict__ bucket_base,
                                   int* __restrict__ fill,
                                   int* __restrict__ row_ptr) {
    __shared__ int s[512];
    __shared__ int ss[256];
    int tid = threadIdx.x;
    int v0 = (2 * tid     < NSUP) ? bucket_cnt[2 * tid]     : 0;
    int v1 = (2 * tid + 1 < NSUP) ? bucket_cnt[2 * tid + 1] : 0;
    ss[tid] = v0 + v1;
    __syncthreads();
    for (int off = 1; off < 256; off <<= 1) {
        int t = (tid >= off) ? ss[tid - off] : 0;
        __syncthreads();
        ss[tid] += t;
        __syncthreads();
    }
    int base = (tid > 0) ? ss[tid - 1] : 0;
    s[2 * tid]     = base;
    s[2 * tid + 1] = base + v0;
    __syncthreads();
    for (int t = tid; t < NSUP; t += 256) {
        bucket_base[t] = s[t];
        fill[t] = s[t];
    }
    if (tid == 0) {
        bucket_base[NSUP] = NEDGES;
        row_ptr[NNODES] = NEDGES;
    }
}

// ---------------------------------------------------------------------------
// K4: partition edges into super-bucket-contiguous tmp arrays (runs ~28 edges)
// ---------------------------------------------------------------------------
__global__ void partition_kernel(const int* __restrict__ edge_src,
                                 const int* __restrict__ edge_dst,
                                 const float* __restrict__ edge_val,
                                 int* __restrict__ fill,
                                 int* __restrict__ tmp_dst,
                                 int2* __restrict__ tmp_sv) {
    __shared__ int h[NSUP];
    for (int t = threadIdx.x; t < NSUP; t += blockDim.x) h[t] = 0;
    __syncthreads();
    int lo = blockIdx.x * CHUNK;
    int hi = min(lo + CHUNK, NEDGES);
    for (int j = lo + (int)threadIdx.x; j < hi; j += blockDim.x)
        atomicAdd(&h[edge_dst[j] >> 9], 1);
    __syncthreads();
    for (int t = threadIdx.x; t < NSUP; t += blockDim.x) {
        int c = h[t];
        h[t] = c ? atomicAdd(&fill[t], c) : 0;   // LDS cursor = my base
    }
    __syncthreads();
    for (int j = lo + (int)threadIdx.x; j < hi; j += blockDim.x) {
        int d = edge_dst[j];
        int pos = atomicAdd(&h[d >> 9], 1);
        tmp_dst[pos] = d;
        tmp_sv[pos]  = make_int2(edge_src[j], __float_as_int(edge_val[j]));
    }
}

// ---------------------------------------------------------------------------
// K5: per-super local counting sort (512 nodes, ~8.2K edges, 64KB out region)
//     -> row_ptr + fully dst-sorted sedge
// ---------------------------------------------------------------------------
__global__ void local_sort_kernel(const int* __restrict__ bucket_base,
                                  const int* __restrict__ tmp_dst,
                                  const int2* __restrict__ tmp_sv,
                                  int* __restrict__ row_ptr,
                                  int2* __restrict__ sedge) {
    __shared__ int h[SPN];
    __shared__ int cur[SPN];
    __shared__ int ss[256];
    int b = blockIdx.x;
    int base = bucket_base[b];
    int end  = bucket_base[b + 1];
    int tid = threadIdx.x;
    h[tid] = 0; h[tid + 256] = 0;
    __syncthreads();
    for (int j = base + tid; j < end; j += 256)
        atomicAdd(&h[tmp_dst[j] & (SPN - 1)], 1);
    __syncthreads();
    int v0 = h[2 * tid], v1 = h[2 * tid + 1];
    ss[tid] = v0 + v1;
    __syncthreads();
    for (int off = 1; off < 256; off <<= 1) {
        int t = (tid >= off) ? ss[tid - off] : 0;
        __syncthreads();
        ss[tid] += t;
        __syncthreads();
    }
    int ebase = (tid > 0) ? ss[tid - 1] : 0;
    int e0 = base + ebase;
    int e1 = base + ebase + v0;
    cur[2 * tid]     = e0;
    cur[2 * tid + 1] = e1;
    int n0 = b * SPN + 2 * tid;
    if (n0     < NNODES) row_ptr[n0]     = e0;
    if (n0 + 1 < NNODES) row_ptr[n0 + 1] = e1;
    __syncthreads();
    for (int j = base + tid; j < end; j += 256) {
        int d = tmp_dst[j];
        int2 sv = tmp_sv[j];
        int pos = atomicAdd(&cur[d & (SPN - 1)], 1);
        sedge[pos] = sv;
    }
}

// ---------------------------------------------------------------------------
// gather SpMM: 16 lanes per dst row, each owns a float4 of the 64-dim row.
// ---------------------------------------------------------------------------
template<bool WRITE_NEXT>
__global__ void spmm_kernel(const int* __restrict__ row_ptr,
                            const int2* __restrict__ sedge,
                            const float* __restrict__ cur,
                            float* __restrict__ next,
                            float* __restrict__ acc) {
    long t = (long)blockIdx.x * blockDim.x + threadIdx.x;
    int row = (int)(t >> 4);
    if (row >= NNODES) return;
    int k = ((int)t & 15) * 4;
    int start = row_ptr[row];
    int end   = row_ptr[row + 1];
    float4 s = make_float4(0.f, 0.f, 0.f, 0.f);
    for (int j = start; j < end; ++j) {
        int2 e = sedge[j];
        float v = __int_as_float(e.y);
        float4 x = *(const float4*)&cur[(long)e.x * DIM + k];
        s.x += v * x.x; s.y += v * x.y; s.z += v * x.z; s.w += v * x.w;
    }
    long o = (long)row * DIM + k;
    if (WRITE_NEXT) *(float4*)&next[o] = s;
    float4 a = *(float4*)&acc[o];
    a.x += s.x; a.y += s.y; a.z += s.z; a.w += s.w;
    *(float4*)&acc[o] = a;
}

// ---------------------------------------------------------------------------
// epilogue: one wave per batch elem; gamma = dot(acc_u, acc_i)/16; sigmoid
// ---------------------------------------------------------------------------
__global__ void dot_kernel(const float* __restrict__ acc,
                           const int* __restrict__ users,
                           const int* __restrict__ items,
                           float* __restrict__ out) {
    int w = (int)(((long)blockIdx.x * blockDim.x + threadIdx.x) >> 6);
    int lane = threadIdx.x & 63;
    if (w >= BATCH) return;
    int u = users[w];
    int it = items[w];
    float a = acc[(long)u * DIM + lane];
    float b = acc[((long)USER_NUM + it) * DIM + lane];
    float p = a * b;
    #pragma unroll
    for (int off = 32; off; off >>= 1) p += __shfl_down(p, off);
    if (lane == 0) {
        float gamma = p * (1.0f / 16.0f);
        out[w] = 1.0f / (1.0f + __expf(-gamma));
    }
}

extern "C" void kernel_launch(void* const* d_in, const int* in_sizes, int n_in,
                              void* d_out, int out_size, void* d_ws, size_t ws_size,
                              hipStream_t stream) {
    const float* user_emb = (const float*)d_in[0];
    const float* item_emb = (const float*)d_in[1];
    const int*   edge_src = (const int*)d_in[2];
    const int*   edge_dst = (const int*)d_in[3];
    const float* edge_val = (const float*)d_in[4];
    const int*   users    = (const int*)d_in[5];
    const int*   items    = (const int*)d_in[6];
    float* out = (float*)d_out;

    const size_t tbl = (size_t)NNODES * DIM * sizeof(float);  // 38.4 MB
    char* w = (char*)d_ws;
    float* acc         = (float*)w;  w += tbl;
    float* bufA        = (float*)w;  w += tbl;
    float* bufB        = (float*)w;  w += tbl;
    int2*  sedge       = (int2*)w;   w += (size_t)NEDGES * 8;
    int*   row_ptr     = (int*)w;    w += ((size_t)NNODES + 16) * 4;
    int*   bucket_cnt  = (int*)w;    w += ((size_t)NSUP + 8) * 4;
    int*   bucket_base = (int*)w;    w += ((size_t)NSUP + 8) * 4;
    int*   fill        = (int*)w;    w += ((size_t)NSUP + 8) * 4;
    // tmp arrays alias bufA/bufB: dead once local_sort completes, before init
    int*   tmp_dst = (int*)bufA;     // 9.6 MB
    int2*  tmp_sv  = (int2*)bufB;    // 19.2 MB

    // ---- CSR build ----
    hipMemsetAsync(bucket_cnt, 0, (size_t)NSUP * 4, stream);
    bucket_hist_kernel<<<NBLK, 256, 0, stream>>>(edge_dst, bucket_cnt);
    bucket_scan_kernel<<<1, 256, 0, stream>>>(bucket_cnt, bucket_base, fill, row_ptr);
    partition_kernel<<<NBLK, 256, 0, stream>>>(edge_src, edge_dst, edge_val,
                                               fill, tmp_dst, tmp_sv);
    local_sort_kernel<<<NSUP, 256, 0, stream>>>(bucket_base, tmp_dst, tmp_sv,
                                                row_ptr, sedge);

    // ---- init (after tmp aliases are dead) ----
    {
        long total4 = (long)NNODES * DIM / 4;
        init_kernel<<<(unsigned)((total4 + 255) / 256), 256, 0, stream>>>(
            user_emb, item_emb, bufA, acc);
    }

    // ---- 3 SpMM layers (gather, fused acc) ----
    const unsigned spmm_grid = (unsigned)(((long)NNODES * 16 + 255) / 256);
    spmm_kernel<true ><<<spmm_grid, 256, 0, stream>>>(row_ptr, sedge, bufA, bufB, acc);
    spmm_kernel<true ><<<spmm_grid, 256, 0, stream>>>(row_ptr, sedge, bufB, bufA, acc);
    spmm_kernel<false><<<spmm_grid, 256, 0, stream>>>(row_ptr, sedge, bufA, bufB, acc);

    // ---- epilogue ----
    dot_kernel<<<(BATCH * 64 + 255) / 256, 256, 0, stream>>>(acc, users, items, out);
}

// Round 5
// 428.582 us; speedup vs baseline: 14.3428x; 1.0445x over previous
//
#include <hip/hip_runtime.h>
#include <hip/hip_bf16.h>

#define USER_NUM 100000
#define ITEM_NUM 50000
#define NNODES   150000
#define DIM      64
#define NEDGES   2400000
#define BATCH    4096

#define SPN      512                            // nodes per super-bucket (dst>>9)
#define NSUP     ((NNODES + SPN - 1) / SPN)     // 293 super-buckets
#define CHUNK    8192
#define NBLK     ((NEDGES + CHUNK - 1) / CHUNK) // 293 blocks

// ---------------------------------------------------------------------------
// init: cur = acc = concat(user_emb, item_emb), float4-vectorized
// ---------------------------------------------------------------------------
__global__ void init_kernel(const float* __restrict__ user_emb,
                            const float* __restrict__ item_emb,
                            float* __restrict__ cur,
                            float* __restrict__ acc) {
    const long total4 = (long)NNODES * DIM / 4;
    long i = (long)blockIdx.x * blockDim.x + threadIdx.x;
    if (i >= total4) return;
    const long user4 = (long)USER_NUM * DIM / 4;
    float4 v;
    if (i < user4) v = ((const float4*)user_emb)[i];
    else           v = ((const float4*)item_emb)[i - user4];
    ((float4*)cur)[i] = v;
    ((float4*)acc)[i] = v;
}

// ---------------------------------------------------------------------------
// K2: per-block LDS hist of dst super-buckets -> global bucket_cnt
// ---------------------------------------------------------------------------
__global__ void bucket_hist_kernel(const int* __restrict__ edge_dst,
                                   int* __restrict__ bucket_cnt) {
    __shared__ int h[NSUP];
    for (int t = threadIdx.x; t < NSUP; t += blockDim.x) h[t] = 0;
    __syncthreads();
    int lo = blockIdx.x * CHUNK;
    int hi = min(lo + CHUNK, NEDGES);
    for (int j = lo + (int)threadIdx.x; j < hi; j += blockDim.x)
        atomicAdd(&h[edge_dst[j] >> 9], 1);
    __syncthreads();
    for (int t = threadIdx.x; t < NSUP; t += blockDim.x)
        if (h[t]) atomicAdd(&bucket_cnt[t], h[t]);
}

// ---------------------------------------------------------------------------
// K3: exclusive scan of bucket_cnt (NSUP=293) in one block, 2 elems/thread
// ---------------------------------------------------------------------------
__global__ void bucket_scan_kernel(const int* __restrict__ bucket_cnt,
                                   int* __restrict__ bucket_base,
                                   int* __restrict__ fill,
                                   int* __restrict__ row_ptr) {
    __shared__ int s[512];
    __shared__ int ss[256];
    int tid = threadIdx.x;
    int v0 = (2 * tid     < NSUP) ? bucket_cnt[2 * tid]     : 0;
    int v1 = (2 * tid + 1 < NSUP) ? bucket_cnt[2 * tid + 1] : 0;
    ss[tid] = v0 + v1;
    __syncthreads();
    for (int off = 1; off < 256; off <<= 1) {
        int t = (tid >= off) ? ss[tid - off] : 0;
        __syncthreads();
        ss[tid] += t;
        __syncthreads();
    }
    int base = (tid > 0) ? ss[tid - 1] : 0;
    s[2 * tid]     = base;
    s[2 * tid + 1] = base + v0;
    __syncthreads();
    for (int t = tid; t < NSUP; t += 256) {
        bucket_base[t] = s[t];
        fill[t] = s[t];
    }
    if (tid == 0) {
        bucket_base[NSUP] = NEDGES;
        row_ptr[NNODES] = NEDGES;
    }
}

// ---------------------------------------------------------------------------
// K4: partition edges into super-bucket-contiguous tmp arrays
// ---------------------------------------------------------------------------
__global__ void partition_kernel(const int* __restrict__ edge_src,
                                 const int* __restrict__ edge_dst,
                                 const float* __restrict__ edge_val,
                                 int* __restrict__ fill,
                                 int* __restrict__ tmp_dst,
                                 int2* __restrict__ tmp_sv) {
    __shared__ int h[NSUP];
    for (int t = threadIdx.x; t < NSUP; t += blockDim.x) h[t] = 0;
    __syncthreads();
    int lo = blockIdx.x * CHUNK;
    int hi = min(lo + CHUNK, NEDGES);
    for (int j = lo + (int)threadIdx.x; j < hi; j += blockDim.x)
        atomicAdd(&h[edge_dst[j] >> 9], 1);
    __syncthreads();
    for (int t = threadIdx.x; t < NSUP; t += blockDim.x) {
        int c = h[t];
        h[t] = c ? atomicAdd(&fill[t], c) : 0;   // LDS cursor = my base
    }
    __syncthreads();
    for (int j = lo + (int)threadIdx.x; j < hi; j += blockDim.x) {
        int d = edge_dst[j];
        int pos = atomicAdd(&h[d >> 9], 1);
        tmp_dst[pos] = d;
        tmp_sv[pos]  = make_int2(edge_src[j], __float_as_int(edge_val[j]));
    }
}

// ---------------------------------------------------------------------------
// K5: per-super local counting sort (512 nodes, ~8.2K edges, 64KB out region)
// ---------------------------------------------------------------------------
__global__ void local_sort_kernel(const int* __restrict__ bucket_base,
                                  const int* __restrict__ tmp_dst,
                                  const int2* __restrict__ tmp_sv,
                                  int* __restrict__ row_ptr,
                                  int2* __restrict__ sedge) {
    __shared__ int h[SPN];
    __shared__ int cur[SPN];
    __shared__ int ss[256];
    int b = blockIdx.x;
    int base = bucket_base[b];
    int end  = bucket_base[b + 1];
    int tid = threadIdx.x;
    h[tid] = 0; h[tid + 256] = 0;
    __syncthreads();
    for (int j = base + tid; j < end; j += 256)
        atomicAdd(&h[tmp_dst[j] & (SPN - 1)], 1);
    __syncthreads();
    int v0 = h[2 * tid], v1 = h[2 * tid + 1];
    ss[tid] = v0 + v1;
    __syncthreads();
    for (int off = 1; off < 256; off <<= 1) {
        int t = (tid >= off) ? ss[tid - off] : 0;
        __syncthreads();
        ss[tid] += t;
        __syncthreads();
    }
    int ebase = (tid > 0) ? ss[tid - 1] : 0;
    int e0 = base + ebase;
    int e1 = base + ebase + v0;
    cur[2 * tid]     = e0;
    cur[2 * tid + 1] = e1;
    int n0 = b * SPN + 2 * tid;
    if (n0     < NNODES) row_ptr[n0]     = e0;
    if (n0 + 1 < NNODES) row_ptr[n0 + 1] = e1;
    __syncthreads();
    for (int j = base + tid; j < end; j += 256) {
        int d = tmp_dst[j];
        int2 sv = tmp_sv[j];
        int pos = atomicAdd(&cur[d & (SPN - 1)], 1);
        sedge[pos] = sv;
    }
}

// ---------------------------------------------------------------------------
// gather SpMM: 16 lanes per dst row, each owns a float4 of the 64-dim row.
// Edge loop unrolled x4: 4 independent gathers in flight per wave.
// ---------------------------------------------------------------------------
template<bool WRITE_NEXT>
__global__ void spmm_kernel(const int* __restrict__ row_ptr,
                            const int2* __restrict__ sedge,
                            const float* __restrict__ cur,
                            float* __restrict__ next,
                            float* __restrict__ acc) {
    long t = (long)blockIdx.x * blockDim.x + threadIdx.x;
    int row = (int)(t >> 4);
    if (row >= NNODES) return;
    int k = ((int)t & 15) * 4;
    int start = row_ptr[row];
    int end   = row_ptr[row + 1];
    float4 s0 = make_float4(0.f, 0.f, 0.f, 0.f);
    float4 s1 = s0, s2 = s0, s3 = s0;
    int j = start;
    for (; j + 4 <= end; j += 4) {
        int2 e0 = sedge[j];
        int2 e1 = sedge[j + 1];
        int2 e2 = sedge[j + 2];
        int2 e3 = sedge[j + 3];
        float4 x0 = *(const float4*)&cur[(long)e0.x * DIM + k];
        float4 x1 = *(const float4*)&cur[(long)e1.x * DIM + k];
        float4 x2 = *(const float4*)&cur[(long)e2.x * DIM + k];
        float4 x3 = *(const float4*)&cur[(long)e3.x * DIM + k];
        float v0 = __int_as_float(e0.y), v1 = __int_as_float(e1.y);
        float v2 = __int_as_float(e2.y), v3 = __int_as_float(e3.y);
        s0.x += v0 * x0.x; s0.y += v0 * x0.y; s0.z += v0 * x0.z; s0.w += v0 * x0.w;
        s1.x += v1 * x1.x; s1.y += v1 * x1.y; s1.z += v1 * x1.z; s1.w += v1 * x1.w;
        s2.x += v2 * x2.x; s2.y += v2 * x2.y; s2.z += v2 * x2.z; s2.w += v2 * x2.w;
        s3.x += v3 * x3.x; s3.y += v3 * x3.y; s3.z += v3 * x3.z; s3.w += v3 * x3.w;
    }
    for (; j < end; ++j) {
        int2 e = sedge[j];
        float v = __int_as_float(e.y);
        float4 x = *(const float4*)&cur[(long)e.x * DIM + k];
        s0.x += v * x.x; s0.y += v * x.y; s0.z += v * x.z; s0.w += v * x.w;
    }
    float4 s;
    s.x = (s0.x + s1.x) + (s2.x + s3.x);
    s.y = (s0.y + s1.y) + (s2.y + s3.y);
    s.z = (s0.z + s1.z) + (s2.z + s3.z);
    s.w = (s0.w + s1.w) + (s2.w + s3.w);
    long o = (long)row * DIM + k;
    if (WRITE_NEXT) *(float4*)&next[o] = s;
    float4 a = *(float4*)&acc[o];
    a.x += s.x; a.y += s.y; a.z += s.z; a.w += s.w;
    *(float4*)&acc[o] = a;
}

// ---------------------------------------------------------------------------
// epilogue: one wave per batch elem; gamma = dot(acc_u, acc_i)/16; sigmoid
// ---------------------------------------------------------------------------
__global__ void dot_kernel(const float* __restrict__ acc,
                           const int* __restrict__ users,
                           const int* __restrict__ items,
                           float* __restrict__ out) {
    int w = (int)(((long)blockIdx.x * blockDim.x + threadIdx.x) >> 6);
    int lane = threadIdx.x & 63;
    if (w >= BATCH) return;
    int u = users[w];
    int it = items[w];
    float a = acc[(long)u * DIM + lane];
    float b = acc[((long)USER_NUM + it) * DIM + lane];
    float p = a * b;
    #pragma unroll
    for (int off = 32; off; off >>= 1) p += __shfl_down(p, off);
    if (lane == 0) {
        float gamma = p * (1.0f / 16.0f);
        out[w] = 1.0f / (1.0f + __expf(-gamma));
    }
}

extern "C" void kernel_launch(void* const* d_in, const int* in_sizes, int n_in,
                              void* d_out, int out_size, void* d_ws, size_t ws_size,
                              hipStream_t stream) {
    const float* user_emb = (const float*)d_in[0];
    const float* item_emb = (const float*)d_in[1];
    const int*   edge_src = (const int*)d_in[2];
    const int*   edge_dst = (const int*)d_in[3];
    const float* edge_val = (const float*)d_in[4];
    const int*   users    = (const int*)d_in[5];
    const int*   items    = (const int*)d_in[6];
    float* out = (float*)d_out;

    const size_t tbl = (size_t)NNODES * DIM * sizeof(float);  // 38.4 MB
    char* w = (char*)d_ws;
    float* acc         = (float*)w;  w += tbl;
    float* bufA        = (float*)w;  w += tbl;
    float* bufB        = (float*)w;  w += tbl;
    int2*  sedge       = (int2*)w;   w += (size_t)NEDGES * 8;
    int*   row_ptr     = (int*)w;    w += ((size_t)NNODES + 16) * 4;
    int*   bucket_cnt  = (int*)w;    w += ((size_t)NSUP + 8) * 4;
    int*   bucket_base = (int*)w;    w += ((size_t)NSUP + 8) * 4;
    int*   fill        = (int*)w;    w += ((size_t)NSUP + 8) * 4;
    // tmp arrays alias bufA/bufB: dead once local_sort completes, before init
    int*   tmp_dst = (int*)bufA;     // 9.6 MB
    int2*  tmp_sv  = (int2*)bufB;    // 19.2 MB

    // ---- CSR build ----
    hipMemsetAsync(bucket_cnt, 0, (size_t)NSUP * 4, stream);
    bucket_hist_kernel<<<NBLK, 256, 0, stream>>>(edge_dst, bucket_cnt);
    bucket_scan_kernel<<<1, 256, 0, stream>>>(bucket_cnt, bucket_base, fill, row_ptr);
    partition_kernel<<<NBLK, 256, 0, stream>>>(edge_src, edge_dst, edge_val,
                                               fill, tmp_dst, tmp_sv);
    local_sort_kernel<<<NSUP, 256, 0, stream>>>(bucket_base, tmp_dst, tmp_sv,
                                                row_ptr, sedge);

    // ---- init (after tmp aliases are dead) ----
    {
        long total4 = (long)NNODES * DIM / 4;
        init_kernel<<<(unsigned)((total4 + 255) / 256), 256, 0, stream>>>(
            user_emb, item_emb, bufA, acc);
    }

    // ---- 3 SpMM layers (gather, fused acc) ----
    const unsigned spmm_grid = (unsigned)(((long)NNODES * 16 + 255) / 256);
    spmm_kernel<true ><<<spmm_grid, 256, 0, stream>>>(row_ptr, sedge, bufA, bufB, acc);
    spmm_kernel<true ><<<spmm_grid, 256, 0, stream>>>(row_ptr, sedge, bufB, bufA, acc);
    spmm_kernel<false><<<spmm_grid, 256, 0, stream>>>(row_ptr, sedge, bufA, bufB, acc);

    // ---- epilogue ----
    dot_kernel<<<(BATCH * 64 + 255) / 256, 256, 0, stream>>>(acc, users, items, out);
}

// Round 6
// 303.729 us; speedup vs baseline: 20.2387x; 1.4111x over previous
//
#include <hip/hip_runtime.h>
#include <hip/hip_bf16.h>
#include <hip/hip_fp16.h>

#define USER_NUM 100000
#define ITEM_NUM 50000
#define NNODES   150000
#define DIM      64
#define NEDGES   2400000
#define BATCH    4096

#define SPN      1024                           // nodes per super-bucket (dst>>10)
#define NSUP     ((NNODES + SPN - 1) / SPN)     // 147 super-buckets
#define CHUNK    4096
#define NBLK     ((NEDGES + CHUNK - 1) / CHUNK) // 586 blocks

__device__ inline float4 h4_to_f4(float2 raw) {
    __half2 a = ((__half2*)&raw)[0];
    __half2 b = ((__half2*)&raw)[1];
    float2 fa = __half22float2(a);
    float2 fb = __half22float2(b);
    return make_float4(fa.x, fa.y, fb.x, fb.y);
}

__device__ inline float2 f4_to_h4(float4 s) {
    __half2 a = __floats2half2_rn(s.x, s.y);
    __half2 b = __floats2half2_rn(s.z, s.w);
    float2 st;
    ((__half2*)&st)[0] = a;
    ((__half2*)&st)[1] = b;
    return st;
}

// ---------------------------------------------------------------------------
// init: acc = concat (fp32), curh = concat (fp16); 1 thread per 4 dims
// ---------------------------------------------------------------------------
__global__ void init_kernel(const float* __restrict__ user_emb,
                            const float* __restrict__ item_emb,
                            __half* __restrict__ curh,
                            float* __restrict__ acc) {
    const long total4 = (long)NNODES * DIM / 4;
    long i = (long)blockIdx.x * blockDim.x + threadIdx.x;
    if (i >= total4) return;
    const long user4 = (long)USER_NUM * DIM / 4;
    float4 v;
    if (i < user4) v = ((const float4*)user_emb)[i];
    else           v = ((const float4*)item_emb)[i - user4];
    ((float4*)acc)[i] = v;
    ((float2*)curh)[i] = f4_to_h4(v);
}

// ---------------------------------------------------------------------------
// K2: per-block LDS hist of dst super-buckets -> global bucket_cnt
// ---------------------------------------------------------------------------
__global__ void bucket_hist_kernel(const int* __restrict__ edge_dst,
                                   int* __restrict__ bucket_cnt) {
    __shared__ int h[NSUP];
    for (int t = threadIdx.x; t < NSUP; t += blockDim.x) h[t] = 0;
    __syncthreads();
    int lo = blockIdx.x * CHUNK;
    int hi = min(lo + CHUNK, NEDGES);
    for (int j = lo + (int)threadIdx.x; j < hi; j += blockDim.x)
        atomicAdd(&h[edge_dst[j] >> 10], 1);
    __syncthreads();
    for (int t = threadIdx.x; t < NSUP; t += blockDim.x)
        if (h[t]) atomicAdd(&bucket_cnt[t], h[t]);
}

// ---------------------------------------------------------------------------
// K3: exclusive scan of bucket_cnt (NSUP=147 <= 256) in one block
// ---------------------------------------------------------------------------
__global__ void bucket_scan_kernel(const int* __restrict__ bucket_cnt,
                                   int* __restrict__ bucket_base,
                                   int* __restrict__ fill,
                                   int* __restrict__ row_ptr) {
    __shared__ int s[256];
    int tid = threadIdx.x;
    int v = (tid < NSUP) ? bucket_cnt[tid] : 0;
    s[tid] = v;
    __syncthreads();
    for (int off = 1; off < 256; off <<= 1) {
        int t = (tid >= off) ? s[tid - off] : 0;
        __syncthreads();
        s[tid] += t;
        __syncthreads();
    }
    if (tid < NSUP) {
        int excl = s[tid] - v;
        bucket_base[tid] = excl;
        fill[tid] = excl;
    }
    if (tid == 0) {
        bucket_base[NSUP] = NEDGES;
        row_ptr[NNODES] = NEDGES;
    }
}

// ---------------------------------------------------------------------------
// K4: partition edges into super-bucket-contiguous tmp (single int4 store)
// ---------------------------------------------------------------------------
__global__ void partition_kernel(const int* __restrict__ edge_src,
                                 const int* __restrict__ edge_dst,
                                 const float* __restrict__ edge_val,
                                 int* __restrict__ fill,
                                 int4* __restrict__ tmp) {
    __shared__ int h[NSUP];
    for (int t = threadIdx.x; t < NSUP; t += blockDim.x) h[t] = 0;
    __syncthreads();
    int lo = blockIdx.x * CHUNK;
    int hi = min(lo + CHUNK, NEDGES);
    for (int j = lo + (int)threadIdx.x; j < hi; j += blockDim.x)
        atomicAdd(&h[edge_dst[j] >> 10], 1);
    __syncthreads();
    for (int t = threadIdx.x; t < NSUP; t += blockDim.x) {
        int c = h[t];
        h[t] = c ? atomicAdd(&fill[t], c) : 0;   // LDS cursor = my base
    }
    __syncthreads();
    for (int j = lo + (int)threadIdx.x; j < hi; j += blockDim.x) {
        int d = edge_dst[j];
        int pos = atomicAdd(&h[d >> 10], 1);
        tmp[pos] = make_int4(edge_src[j], __float_as_int(edge_val[j]), d, 0);
    }
}

// ---------------------------------------------------------------------------
// K5: per-super local counting sort (1024 nodes, ~16K edges)
//     -> row_ptr + fully dst-sorted sedge
// ---------------------------------------------------------------------------
__global__ void local_sort_kernel(const int* __restrict__ bucket_base,
                                  const int4* __restrict__ tmp,
                                  int* __restrict__ row_ptr,
                                  int2* __restrict__ sedge) {
    __shared__ int h[SPN];
    __shared__ int cur[SPN];
    __shared__ int ss[256];
    int b = blockIdx.x;
    int base = bucket_base[b];
    int end  = bucket_base[b + 1];
    int tid = threadIdx.x;
    #pragma unroll
    for (int q = 0; q < 4; ++q) h[tid + 256 * q] = 0;
    __syncthreads();
    for (int j = base + tid; j < end; j += 256)
        atomicAdd(&h[tmp[j].z & (SPN - 1)], 1);
    __syncthreads();
    int v0 = h[4 * tid], v1 = h[4 * tid + 1], v2 = h[4 * tid + 2], v3 = h[4 * tid + 3];
    ss[tid] = v0 + v1 + v2 + v3;
    __syncthreads();
    for (int off = 1; off < 256; off <<= 1) {
        int t = (tid >= off) ? ss[tid - off] : 0;
        __syncthreads();
        ss[tid] += t;
        __syncthreads();
    }
    int ebase = (tid > 0) ? ss[tid - 1] : 0;
    int e0 = base + ebase;
    int e1 = e0 + v0;
    int e2 = e1 + v1;
    int e3 = e2 + v2;
    cur[4 * tid]     = e0;
    cur[4 * tid + 1] = e1;
    cur[4 * tid + 2] = e2;
    cur[4 * tid + 3] = e3;
    int n0 = b * SPN + 4 * tid;
    if (n0     < NNODES) row_ptr[n0]     = e0;
    if (n0 + 1 < NNODES) row_ptr[n0 + 1] = e1;
    if (n0 + 2 < NNODES) row_ptr[n0 + 2] = e2;
    if (n0 + 3 < NNODES) row_ptr[n0 + 3] = e3;
    __syncthreads();
    for (int j = base + tid; j < end; j += 256) {
        int4 e = tmp[j];
        int pos = atomicAdd(&cur[e.z & (SPN - 1)], 1);
        sedge[pos] = make_int2(e.x, e.y);
    }
}

// ---------------------------------------------------------------------------
// gather SpMM (fp16 table): 16 lanes per dst row, 4 dims (8 B) per lane.
// fp32 accumulate; writes next as fp16, acc RMW fp32. Unroll x4.
// ---------------------------------------------------------------------------
template<bool WRITE_NEXT>
__global__ void spmm_kernel(const int* __restrict__ row_ptr,
                            const int2* __restrict__ sedge,
                            const __half* __restrict__ cur,
                            __half* __restrict__ next,
                            float* __restrict__ acc) {
    long t = (long)blockIdx.x * blockDim.x + threadIdx.x;
    int row = (int)(t >> 4);
    if (row >= NNODES) return;
    int k = ((int)t & 15) * 4;
    int start = row_ptr[row];
    int end   = row_ptr[row + 1];
    float4 s0 = make_float4(0.f, 0.f, 0.f, 0.f);
    float4 s1 = s0, s2 = s0, s3 = s0;
    int j = start;
    for (; j + 4 <= end; j += 4) {
        int2 e0 = sedge[j];
        int2 e1 = sedge[j + 1];
        int2 e2 = sedge[j + 2];
        int2 e3 = sedge[j + 3];
        float2 r0 = *(const float2*)&cur[(long)e0.x * DIM + k];
        float2 r1 = *(const float2*)&cur[(long)e1.x * DIM + k];
        float2 r2 = *(const float2*)&cur[(long)e2.x * DIM + k];
        float2 r3 = *(const float2*)&cur[(long)e3.x * DIM + k];
        float4 x0 = h4_to_f4(r0), x1 = h4_to_f4(r1);
        float4 x2 = h4_to_f4(r2), x3 = h4_to_f4(r3);
        float v0 = __int_as_float(e0.y), v1 = __int_as_float(e1.y);
        float v2 = __int_as_float(e2.y), v3 = __int_as_float(e3.y);
        s0.x += v0 * x0.x; s0.y += v0 * x0.y; s0.z += v0 * x0.z; s0.w += v0 * x0.w;
        s1.x += v1 * x1.x; s1.y += v1 * x1.y; s1.z += v1 * x1.z; s1.w += v1 * x1.w;
        s2.x += v2 * x2.x; s2.y += v2 * x2.y; s2.z += v2 * x2.z; s2.w += v2 * x2.w;
        s3.x += v3 * x3.x; s3.y += v3 * x3.y; s3.z += v3 * x3.z; s3.w += v3 * x3.w;
    }
    for (; j < end; ++j) {
        int2 e = sedge[j];
        float v = __int_as_float(e.y);
        float4 x = h4_to_f4(*(const float2*)&cur[(long)e.x * DIM + k]);
        s0.x += v * x.x; s0.y += v * x.y; s0.z += v * x.z; s0.w += v * x.w;
    }
    float4 s;
    s.x = (s0.x + s1.x) + (s2.x + s3.x);
    s.y = (s0.y + s1.y) + (s2.y + s3.y);
    s.z = (s0.z + s1.z) + (s2.z + s3.z);
    s.w = (s0.w + s1.w) + (s2.w + s3.w);
    long o = (long)row * DIM + k;
    if (WRITE_NEXT) *(float2*)&next[o] = f4_to_h4(s);
    float4 a = *(float4*)&acc[o];
    a.x += s.x; a.y += s.y; a.z += s.z; a.w += s.w;
    *(float4*)&acc[o] = a;
}

// ---------------------------------------------------------------------------
// epilogue: one wave per batch elem; gamma = dot(acc_u, acc_i)/16; sigmoid
// ---------------------------------------------------------------------------
__global__ void dot_kernel(const float* __restrict__ acc,
                           const int* __restrict__ users,
                           const int* __restrict__ items,
                           float* __restrict__ out) {
    int w = (int)(((long)blockIdx.x * blockDim.x + threadIdx.x) >> 6);
    int lane = threadIdx.x & 63;
    if (w >= BATCH) return;
    int u = users[w];
    int it = items[w];
    float a = acc[(long)u * DIM + lane];
    float b = acc[((long)USER_NUM + it) * DIM + lane];
    float p = a * b;
    #pragma unroll
    for (int off = 32; off; off >>= 1) p += __shfl_down(p, off);
    if (lane == 0) {
        float gamma = p * (1.0f / 16.0f);
        out[w] = 1.0f / (1.0f + __expf(-gamma));
    }
}

extern "C" void kernel_launch(void* const* d_in, const int* in_sizes, int n_in,
                              void* d_out, int out_size, void* d_ws, size_t ws_size,
                              hipStream_t stream) {
    const float* user_emb = (const float*)d_in[0];
    const float* item_emb = (const float*)d_in[1];
    const int*   edge_src = (const int*)d_in[2];
    const int*   edge_dst = (const int*)d_in[3];
    const float* edge_val = (const float*)d_in[4];
    const int*   users    = (const int*)d_in[5];
    const int*   items    = (const int*)d_in[6];
    float* out = (float*)d_out;

    const size_t tbl  = (size_t)NNODES * DIM * sizeof(float);   // 38.4 MB (fp32)
    const size_t htbl = (size_t)NNODES * DIM * sizeof(__half);  // 19.2 MB (fp16)
    char* w = (char*)d_ws;
    float*  acc         = (float*)w;   w += tbl;
    char*   bufA        = w;           w += tbl;   // tmp int4 (38.4 MB), dead after local_sort
    char*   bufB        = w;           w += tbl;   // curh + nexth (19.2 + 19.2 MB)
    int2*   sedge       = (int2*)w;    w += (size_t)NEDGES * 8;
    int*    row_ptr     = (int*)w;     w += ((size_t)NNODES + 16) * 4;
    int*    bucket_cnt  = (int*)w;     w += ((size_t)NSUP + 8) * 4;
    int*    bucket_base = (int*)w;     w += ((size_t)NSUP + 8) * 4;
    int*    fill        = (int*)w;     w += ((size_t)NSUP + 8) * 4;

    int4*   tmp   = (int4*)bufA;                  // 2.4M x 16 B = 38.4 MB
    __half* tabA  = (__half*)bufB;                // 19.2 MB
    __half* tabB  = (__half*)(bufB + htbl);       // 19.2 MB

    // ---- CSR build ----
    hipMemsetAsync(bucket_cnt, 0, (size_t)NSUP * 4, stream);
    bucket_hist_kernel<<<NBLK, 256, 0, stream>>>(edge_dst, bucket_cnt);
    bucket_scan_kernel<<<1, 256, 0, stream>>>(bucket_cnt, bucket_base, fill, row_ptr);
    partition_kernel<<<NBLK, 256, 0, stream>>>(edge_src, edge_dst, edge_val, fill, tmp);
    local_sort_kernel<<<NSUP, 256, 0, stream>>>(bucket_base, tmp, row_ptr, sedge);

    // ---- init ----
    {
        long total4 = (long)NNODES * DIM / 4;
        init_kernel<<<(unsigned)((total4 + 255) / 256), 256, 0, stream>>>(
            user_emb, item_emb, tabA, acc);
    }

    // ---- 3 SpMM layers (fp16 gather, fp32 accumulate) ----
    const unsigned spmm_grid = (unsigned)(((long)NNODES * 16 + 255) / 256);
    spmm_kernel<true ><<<spmm_grid, 256, 0, stream>>>(row_ptr, sedge, tabA, tabB, acc);
    spmm_kernel<true ><<<spmm_grid, 256, 0, stream>>>(row_ptr, sedge, tabB, tabA, acc);
    spmm_kernel<false><<<spmm_grid, 256, 0, stream>>>(row_ptr, sedge, tabA, tabB, acc);

    // ---- epilogue ----
    dot_kernel<<<(BATCH * 64 + 255) / 256, 256, 0, stream>>>(acc, users, items, out);
}

// Round 7
// 242.347 us; speedup vs baseline: 25.3648x; 1.2533x over previous
//
#include <hip/hip_runtime.h>
#include <hip/hip_bf16.h>
#include <hip/hip_fp16.h>

#define USER_NUM 100000
#define ITEM_NUM 50000
#define NNODES   150000
#define DIM      64
#define NEDGES   2400000
#define BATCH    4096

#define SPN      1024                           // nodes per super-bucket (dst>>10)
#define NSUP     ((NNODES + SPN - 1) / SPN)     // 147 super-buckets
#define CHUNK    4096
#define NBLK     ((NEDGES + CHUNK - 1) / CHUNK) // 586 blocks

__device__ inline float4 h4_to_f4(float2 raw) {
    __half2 a = ((__half2*)&raw)[0];
    __half2 b = ((__half2*)&raw)[1];
    float2 fa = __half22float2(a);
    float2 fb = __half22float2(b);
    return make_float4(fa.x, fa.y, fb.x, fb.y);
}

__device__ inline float2 f4_to_h4(float4 s) {
    __half2 a = __floats2half2_rn(s.x, s.y);
    __half2 b = __floats2half2_rn(s.z, s.w);
    float2 st;
    ((__half2*)&st)[0] = a;
    ((__half2*)&st)[1] = b;
    return st;
}

// ---------------------------------------------------------------------------
// init: tabA = concat(user_emb, item_emb) in fp16
// ---------------------------------------------------------------------------
__global__ void init_kernel(const float* __restrict__ user_emb,
                            const float* __restrict__ item_emb,
                            __half* __restrict__ curh) {
    const long total4 = (long)NNODES * DIM / 4;
    long i = (long)blockIdx.x * blockDim.x + threadIdx.x;
    if (i >= total4) return;
    const long user4 = (long)USER_NUM * DIM / 4;
    float4 v;
    if (i < user4) v = ((const float4*)user_emb)[i];
    else           v = ((const float4*)item_emb)[i - user4];
    ((float2*)curh)[i] = f4_to_h4(v);
}

// ---------------------------------------------------------------------------
// sampled acc init: acc_s[slot] = e0 at sampled node (fp32 from orig emb)
// ---------------------------------------------------------------------------
__global__ void sample_init_kernel(const float* __restrict__ user_emb,
                                   const float* __restrict__ item_emb,
                                   const int* __restrict__ users,
                                   const int* __restrict__ items,
                                   float* __restrict__ acc_s) {
    int t = blockIdx.x * blockDim.x + threadIdx.x;
    int slot = t >> 4;
    if (slot >= 2 * BATCH) return;
    int k = (t & 15) * 4;
    const float* src = (slot < BATCH)
        ? &user_emb[(long)users[slot] * DIM]
        : &item_emb[(long)items[slot - BATCH] * DIM];
    *(float4*)&acc_s[(long)slot * DIM + k] = *(const float4*)&src[k];
}

// ---------------------------------------------------------------------------
// sampled acc update: acc_s[slot] += tab[node] (fp16 -> fp32)
// ---------------------------------------------------------------------------
__global__ void sample_add_kernel(const __half* __restrict__ tab,
                                  const int* __restrict__ users,
                                  const int* __restrict__ items,
                                  float* __restrict__ acc_s) {
    int t = blockIdx.x * blockDim.x + threadIdx.x;
    int slot = t >> 4;
    if (slot >= 2 * BATCH) return;
    int k = (t & 15) * 4;
    int node = (slot < BATCH) ? users[slot] : USER_NUM + items[slot - BATCH];
    float4 x = h4_to_f4(*(const float2*)&tab[(long)node * DIM + k]);
    long o = (long)slot * DIM + k;
    float4 a = *(float4*)&acc_s[o];
    a.x += x.x; a.y += x.y; a.z += x.z; a.w += x.w;
    *(float4*)&acc_s[o] = a;
}

// ---------------------------------------------------------------------------
// K2: per-block LDS hist of dst super-buckets -> global bucket_cnt
// ---------------------------------------------------------------------------
__global__ void bucket_hist_kernel(const int* __restrict__ edge_dst,
                                   int* __restrict__ bucket_cnt) {
    __shared__ int h[NSUP];
    for (int t = threadIdx.x; t < NSUP; t += blockDim.x) h[t] = 0;
    __syncthreads();
    int lo = blockIdx.x * CHUNK;
    int hi = min(lo + CHUNK, NEDGES);
    for (int j = lo + (int)threadIdx.x; j < hi; j += blockDim.x)
        atomicAdd(&h[edge_dst[j] >> 10], 1);
    __syncthreads();
    for (int t = threadIdx.x; t < NSUP; t += blockDim.x)
        if (h[t]) atomicAdd(&bucket_cnt[t], h[t]);
}

// ---------------------------------------------------------------------------
// K3: exclusive scan of bucket_cnt (NSUP=147 <= 256) in one block
// ---------------------------------------------------------------------------
__global__ void bucket_scan_kernel(const int* __restrict__ bucket_cnt,
                                   int* __restrict__ bucket_base,
                                   int* __restrict__ fill,
                                   int* __restrict__ row_ptr) {
    __shared__ int s[256];
    int tid = threadIdx.x;
    int v = (tid < NSUP) ? bucket_cnt[tid] : 0;
    s[tid] = v;
    __syncthreads();
    for (int off = 1; off < 256; off <<= 1) {
        int t = (tid >= off) ? s[tid - off] : 0;
        __syncthreads();
        s[tid] += t;
        __syncthreads();
    }
    if (tid < NSUP) {
        int excl = s[tid] - v;
        bucket_base[tid] = excl;
        fill[tid] = excl;
    }
    if (tid == 0) {
        bucket_base[NSUP] = NEDGES;
        row_ptr[NNODES] = NEDGES;
    }
}

// ---------------------------------------------------------------------------
// K4: partition edges into super-bucket-contiguous tmp (single int4 store)
// ---------------------------------------------------------------------------
__global__ void partition_kernel(const int* __restrict__ edge_src,
                                 const int* __restrict__ edge_dst,
                                 const float* __restrict__ edge_val,
                                 int* __restrict__ fill,
                                 int4* __restrict__ tmp) {
    __shared__ int h[NSUP];
    for (int t = threadIdx.x; t < NSUP; t += blockDim.x) h[t] = 0;
    __syncthreads();
    int lo = blockIdx.x * CHUNK;
    int hi = min(lo + CHUNK, NEDGES);
    for (int j = lo + (int)threadIdx.x; j < hi; j += blockDim.x)
        atomicAdd(&h[edge_dst[j] >> 10], 1);
    __syncthreads();
    for (int t = threadIdx.x; t < NSUP; t += blockDim.x) {
        int c = h[t];
        h[t] = c ? atomicAdd(&fill[t], c) : 0;   // LDS cursor = my base
    }
    __syncthreads();
    for (int j = lo + (int)threadIdx.x; j < hi; j += blockDim.x) {
        int d = edge_dst[j];
        int pos = atomicAdd(&h[d >> 10], 1);
        tmp[pos] = make_int4(edge_src[j], __float_as_int(edge_val[j]), d, 0);
    }
}

// ---------------------------------------------------------------------------
// K5: per-super local counting sort (1024 nodes, ~16K edges)
// ---------------------------------------------------------------------------
__global__ void local_sort_kernel(const int* __restrict__ bucket_base,
                                  const int4* __restrict__ tmp,
                                  int* __restrict__ row_ptr,
                                  int2* __restrict__ sedge) {
    __shared__ int h[SPN];
    __shared__ int cur[SPN];
    __shared__ int ss[256];
    int b = blockIdx.x;
    int base = bucket_base[b];
    int end  = bucket_base[b + 1];
    int tid = threadIdx.x;
    #pragma unroll
    for (int q = 0; q < 4; ++q) h[tid + 256 * q] = 0;
    __syncthreads();
    for (int j = base + tid; j < end; j += 256)
        atomicAdd(&h[tmp[j].z & (SPN - 1)], 1);
    __syncthreads();
    int v0 = h[4 * tid], v1 = h[4 * tid + 1], v2 = h[4 * tid + 2], v3 = h[4 * tid + 3];
    ss[tid] = v0 + v1 + v2 + v3;
    __syncthreads();
    for (int off = 1; off < 256; off <<= 1) {
        int t = (tid >= off) ? ss[tid - off] : 0;
        __syncthreads();
        ss[tid] += t;
        __syncthreads();
    }
    int ebase = (tid > 0) ? ss[tid - 1] : 0;
    int e0 = base + ebase;
    int e1 = e0 + v0;
    int e2 = e1 + v1;
    int e3 = e2 + v2;
    cur[4 * tid]     = e0;
    cur[4 * tid + 1] = e1;
    cur[4 * tid + 2] = e2;
    cur[4 * tid + 3] = e3;
    int n0 = b * SPN + 4 * tid;
    if (n0     < NNODES) row_ptr[n0]     = e0;
    if (n0 + 1 < NNODES) row_ptr[n0 + 1] = e1;
    if (n0 + 2 < NNODES) row_ptr[n0 + 2] = e2;
    if (n0 + 3 < NNODES) row_ptr[n0 + 3] = e3;
    __syncthreads();
    for (int j = base + tid; j < end; j += 256) {
        int4 e = tmp[j];
        int pos = atomicAdd(&cur[e.z & (SPN - 1)], 1);
        sedge[pos] = make_int2(e.x, e.y);
    }
}

// ---------------------------------------------------------------------------
// full gather SpMM (fp16 table): 16 lanes per dst row, unroll x4, no acc
// ---------------------------------------------------------------------------
__global__ void spmm_kernel(const int* __restrict__ row_ptr,
                            const int2* __restrict__ sedge,
                            const __half* __restrict__ cur,
                            __half* __restrict__ next) {
    long t = (long)blockIdx.x * blockDim.x + threadIdx.x;
    int row = (int)(t >> 4);
    if (row >= NNODES) return;
    int k = ((int)t & 15) * 4;
    int start = row_ptr[row];
    int end   = row_ptr[row + 1];
    float4 s0 = make_float4(0.f, 0.f, 0.f, 0.f);
    float4 s1 = s0, s2 = s0, s3 = s0;
    int j = start;
    for (; j + 4 <= end; j += 4) {
        int2 e0 = sedge[j];
        int2 e1 = sedge[j + 1];
        int2 e2 = sedge[j + 2];
        int2 e3 = sedge[j + 3];
        float2 r0 = *(const float2*)&cur[(long)e0.x * DIM + k];
        float2 r1 = *(const float2*)&cur[(long)e1.x * DIM + k];
        float2 r2 = *(const float2*)&cur[(long)e2.x * DIM + k];
        float2 r3 = *(const float2*)&cur[(long)e3.x * DIM + k];
        float4 x0 = h4_to_f4(r0), x1 = h4_to_f4(r1);
        float4 x2 = h4_to_f4(r2), x3 = h4_to_f4(r3);
        float v0 = __int_as_float(e0.y), v1 = __int_as_float(e1.y);
        float v2 = __int_as_float(e2.y), v3 = __int_as_float(e3.y);
        s0.x += v0 * x0.x; s0.y += v0 * x0.y; s0.z += v0 * x0.z; s0.w += v0 * x0.w;
        s1.x += v1 * x1.x; s1.y += v1 * x1.y; s1.z += v1 * x1.z; s1.w += v1 * x1.w;
        s2.x += v2 * x2.x; s2.y += v2 * x2.y; s2.z += v2 * x2.z; s2.w += v2 * x2.w;
        s3.x += v3 * x3.x; s3.y += v3 * x3.y; s3.z += v3 * x3.z; s3.w += v3 * x3.w;
    }
    for (; j < end; ++j) {
        int2 e = sedge[j];
        float v = __int_as_float(e.y);
        float4 x = h4_to_f4(*(const float2*)&cur[(long)e.x * DIM + k]);
        s0.x += v * x.x; s0.y += v * x.y; s0.z += v * x.z; s0.w += v * x.w;
    }
    float4 s;
    s.x = (s0.x + s1.x) + (s2.x + s3.x);
    s.y = (s0.y + s1.y) + (s2.y + s3.y);
    s.z = (s0.z + s1.z) + (s2.z + s3.z);
    s.w = (s0.w + s1.w) + (s2.w + s3.w);
    *(float2*)&next[(long)row * DIM + k] = f4_to_h4(s);
}

// ---------------------------------------------------------------------------
// sampled SpMM (layer 3): only the 8192 sampled rows; acc_s += result
// ---------------------------------------------------------------------------
__global__ void spmm_sampled_kernel(const int* __restrict__ row_ptr,
                                    const int2* __restrict__ sedge,
                                    const __half* __restrict__ cur,
                                    const int* __restrict__ users,
                                    const int* __restrict__ items,
                                    float* __restrict__ acc_s) {
    int t = blockIdx.x * blockDim.x + threadIdx.x;
    int slot = t >> 4;
    if (slot >= 2 * BATCH) return;
    int k = (t & 15) * 4;
    int node = (slot < BATCH) ? users[slot] : USER_NUM + items[slot - BATCH];
    int start = row_ptr[node];
    int end   = row_ptr[node + 1];
    float4 s0 = make_float4(0.f, 0.f, 0.f, 0.f);
    float4 s1 = s0, s2 = s0, s3 = s0;
    int j = start;
    for (; j + 4 <= end; j += 4) {
        int2 e0 = sedge[j];
        int2 e1 = sedge[j + 1];
        int2 e2 = sedge[j + 2];
        int2 e3 = sedge[j + 3];
        float4 x0 = h4_to_f4(*(const float2*)&cur[(long)e0.x * DIM + k]);
        float4 x1 = h4_to_f4(*(const float2*)&cur[(long)e1.x * DIM + k]);
        float4 x2 = h4_to_f4(*(const float2*)&cur[(long)e2.x * DIM + k]);
        float4 x3 = h4_to_f4(*(const float2*)&cur[(long)e3.x * DIM + k]);
        float v0 = __int_as_float(e0.y), v1 = __int_as_float(e1.y);
        float v2 = __int_as_float(e2.y), v3 = __int_as_float(e3.y);
        s0.x += v0 * x0.x; s0.y += v0 * x0.y; s0.z += v0 * x0.z; s0.w += v0 * x0.w;
        s1.x += v1 * x1.x; s1.y += v1 * x1.y; s1.z += v1 * x1.z; s1.w += v1 * x1.w;
        s2.x += v2 * x2.x; s2.y += v2 * x2.y; s2.z += v2 * x2.z; s2.w += v2 * x2.w;
        s3.x += v3 * x3.x; s3.y += v3 * x3.y; s3.z += v3 * x3.z; s3.w += v3 * x3.w;
    }
    for (; j < end; ++j) {
        int2 e = sedge[j];
        float v = __int_as_float(e.y);
        float4 x = h4_to_f4(*(const float2*)&cur[(long)e.x * DIM + k]);
        s0.x += v * x.x; s0.y += v * x.y; s0.z += v * x.z; s0.w += v * x.w;
    }
    long o = (long)slot * DIM + k;
    float4 a = *(float4*)&acc_s[o];
    a.x += (s0.x + s1.x) + (s2.x + s3.x);
    a.y += (s0.y + s1.y) + (s2.y + s3.y);
    a.z += (s0.z + s1.z) + (s2.z + s3.z);
    a.w += (s0.w + s1.w) + (s2.w + s3.w);
    *(float4*)&acc_s[o] = a;
}

// ---------------------------------------------------------------------------
// epilogue: one wave per batch elem; gamma = dot(acc_s_u, acc_s_i)/16
// ---------------------------------------------------------------------------
__global__ void dot_kernel(const float* __restrict__ acc_s,
                           float* __restrict__ out) {
    int w = (int)(((long)blockIdx.x * blockDim.x + threadIdx.x) >> 6);
    int lane = threadIdx.x & 63;
    if (w >= BATCH) return;
    float a = acc_s[(long)w * DIM + lane];
    float b = acc_s[(long)(BATCH + w) * DIM + lane];
    float p = a * b;
    #pragma unroll
    for (int off = 32; off; off >>= 1) p += __shfl_down(p, off);
    if (lane == 0) {
        float gamma = p * (1.0f / 16.0f);
        out[w] = 1.0f / (1.0f + __expf(-gamma));
    }
}

extern "C" void kernel_launch(void* const* d_in, const int* in_sizes, int n_in,
                              void* d_out, int out_size, void* d_ws, size_t ws_size,
                              hipStream_t stream) {
    const float* user_emb = (const float*)d_in[0];
    const float* item_emb = (const float*)d_in[1];
    const int*   edge_src = (const int*)d_in[2];
    const int*   edge_dst = (const int*)d_in[3];
    const float* edge_val = (const float*)d_in[4];
    const int*   users    = (const int*)d_in[5];
    const int*   items    = (const int*)d_in[6];
    float* out = (float*)d_out;

    const size_t tbl  = (size_t)NNODES * DIM * sizeof(float);   // 38.4 MB
    const size_t htbl = (size_t)NNODES * DIM * sizeof(__half);  // 19.2 MB
    char* w = (char*)d_ws;
    float*  acc_s       = (float*)w;   w += tbl;   // uses 2 MB of this region
    char*   bufA        = w;           w += tbl;   // tmp int4, dead after local_sort
    char*   bufB        = w;           w += tbl;   // tabA + tabB
    int2*   sedge       = (int2*)w;    w += (size_t)NEDGES * 8;
    int*    row_ptr     = (int*)w;     w += ((size_t)NNODES + 16) * 4;
    int*    bucket_cnt  = (int*)w;     w += ((size_t)NSUP + 8) * 4;
    int*    bucket_base = (int*)w;     w += ((size_t)NSUP + 8) * 4;
    int*    fill        = (int*)w;     w += ((size_t)NSUP + 8) * 4;

    int4*   tmp   = (int4*)bufA;
    __half* tabA  = (__half*)bufB;
    __half* tabB  = (__half*)(bufB + htbl);

    // ---- CSR build ----
    hipMemsetAsync(bucket_cnt, 0, (size_t)NSUP * 4, stream);
    bucket_hist_kernel<<<NBLK, 256, 0, stream>>>(edge_dst, bucket_cnt);
    bucket_scan_kernel<<<1, 256, 0, stream>>>(bucket_cnt, bucket_base, fill, row_ptr);
    partition_kernel<<<NBLK, 256, 0, stream>>>(edge_src, edge_dst, edge_val, fill, tmp);
    local_sort_kernel<<<NSUP, 256, 0, stream>>>(bucket_base, tmp, row_ptr, sedge);

    // ---- init ----
    {
        long total4 = (long)NNODES * DIM / 4;
        init_kernel<<<(unsigned)((total4 + 255) / 256), 256, 0, stream>>>(
            user_emb, item_emb, tabA);
    }
    const unsigned samp_grid = (2 * BATCH * 16 + 255) / 256;   // 512 blocks
    sample_init_kernel<<<samp_grid, 256, 0, stream>>>(user_emb, item_emb,
                                                      users, items, acc_s);

    // ---- layers ----
    const unsigned spmm_grid = (unsigned)(((long)NNODES * 16 + 255) / 256);
    spmm_kernel<<<spmm_grid, 256, 0, stream>>>(row_ptr, sedge, tabA, tabB);   // e1
    sample_add_kernel<<<samp_grid, 256, 0, stream>>>(tabB, users, items, acc_s);
    spmm_kernel<<<spmm_grid, 256, 0, stream>>>(row_ptr, sedge, tabB, tabA);   // e2
    sample_add_kernel<<<samp_grid, 256, 0, stream>>>(tabA, users, items, acc_s);
    spmm_sampled_kernel<<<samp_grid, 256, 0, stream>>>(row_ptr, sedge, tabA,
                                                       users, items, acc_s);  // e3 @ samples
    // ---- epilogue ----
    dot_kernel<<<(BATCH * 64 + 255) / 256, 256, 0, stream>>>(acc_s, out);
}